// Round 1
// baseline (1916.343 us; speedup 1.0000x reference)
//
#include <hip/hip_runtime.h>
#include <math.h>

// ---------------- dims (fixed by the problem) ----------------
// N=50000, E=800000 (+N self loops), IN=128, HID=256, HEADS=4, C1=64, OUT=128
#define NEG_SLOPE 0.2f

// Monotone float->uint mapping for atomicMax on floats.
__device__ __forceinline__ unsigned fmap(float f) {
    int b = __float_as_int(f);
    return (b >= 0) ? ((unsigned)b | 0x80000000u) : ~(unsigned)b;
}
__device__ __forceinline__ float funmap(unsigned u) {
    int b = (u & 0x80000000u) ? (int)(u & 0x7fffffffu) : (int)~u;
    return __int_as_float(b);
}

__device__ __forceinline__ float lrelu(float t) {
    return t > 0.f ? t : NEG_SLOPE * t;
}

// out[n*C + c] = b[c]   (bias broadcast init of the aggregation buffer)
__global__ void init_bias(float* __restrict__ out, const float* __restrict__ b,
                          long total, int C) {
    long i = (long)blockIdx.x * blockDim.x + threadIdx.x;
    if (i < total) out[i] = b[i & (C - 1)];  // C is 256 or 128 (pow2)
}

__global__ void relu_inplace(float* __restrict__ x, long n) {
    long i = (long)blockIdx.x * blockDim.x + threadIdx.x;
    if (i < n) x[i] = fmaxf(x[i], 0.f);
}

// Y[M,NC] = X[M,K] @ W[K,NC]. Block: NC threads, ROWS rows per block.
template <int K, int NC, int ROWS>
__global__ void gemm_rows(const float* __restrict__ X, const float* __restrict__ W,
                          float* __restrict__ Y, int M) {
    __shared__ float xs[ROWS * K];
    const int j = threadIdx.x;
    const int row0 = blockIdx.x * ROWS;

    // load X tile (float4)
    const int TOT4 = ROWS * K / 4;
    for (int i = j; i < TOT4; i += NC) {
        int r = (i * 4) / K;
        float4 v = make_float4(0.f, 0.f, 0.f, 0.f);
        if (row0 + r < M) v = ((const float4*)X)[(size_t)row0 * (K / 4) + i];
        ((float4*)xs)[i] = v;
    }
    __syncthreads();

    float acc[ROWS];
#pragma unroll
    for (int r = 0; r < ROWS; r++) acc[r] = 0.f;

    for (int k = 0; k < K; k++) {
        float w = W[k * NC + j];
#pragma unroll
        for (int r = 0; r < ROWS; r++) acc[r] += xs[r * K + k] * w;
    }

#pragma unroll
    for (int r = 0; r < ROWS; r++) {
        if (row0 + r < M) Y[(size_t)(row0 + r) * NC + j] = acc[r];
    }
}

// as_out[n,h] = sum_c H[n,h,c]*a_src[h,c]; ad_out likewise. Block = H*C threads.
template <int H, int C>
__global__ void attn_dots(const float* __restrict__ Hf,
                          const float* __restrict__ a_src,
                          const float* __restrict__ a_dst,
                          float* __restrict__ as_out, float* __restrict__ ad_out) {
    const int n = blockIdx.x;
    const int t = threadIdx.x;  // [0, H*C)
    float hv = Hf[(size_t)n * H * C + t];
    float vs = hv * a_src[t];
    float vd = hv * a_dst[t];
#pragma unroll
    for (int off = 32; off > 0; off >>= 1) {
        vs += __shfl_down(vs, off, 64);
        vd += __shfl_down(vd, off, 64);
    }
    __shared__ float ps[H * C / 64], pd[H * C / 64];
    const int wave = t >> 6, lane = t & 63;
    if (lane == 0) { ps[wave] = vs; pd[wave] = vd; }
    __syncthreads();
    if (t < H) {
        float ss = 0.f, dd = 0.f;
#pragma unroll
        for (int w = 0; w < C / 64; w++) {
            ss += ps[t * (C / 64) + w];
            dd += pd[t * (C / 64) + w];
        }
        as_out[n * H + t] = ss;
        ad_out[n * H + t] = dd;
    }
}

template <int H>
__global__ void edge_max(const int* __restrict__ src, const int* __restrict__ dst,
                         const float* __restrict__ as_, const float* __restrict__ ad_,
                         unsigned* __restrict__ m, int E, int N) {
    int e = blockIdx.x * blockDim.x + threadIdx.x;
    if (e >= E + N) return;
    int s = (e < E) ? src[e] : (e - E);
    int d = (e < E) ? dst[e] : (e - E);
#pragma unroll
    for (int h = 0; h < H; h++) {
        float t = lrelu(as_[s * H + h] + ad_[d * H + h]);
        atomicMax(&m[d * H + h], fmap(t));
    }
}

template <int H>
__global__ void edge_expsum(const int* __restrict__ src, const int* __restrict__ dst,
                            const float* __restrict__ as_, const float* __restrict__ ad_,
                            const unsigned* __restrict__ m, float* __restrict__ ex,
                            float* __restrict__ ssum, int E, int N) {
    int e = blockIdx.x * blockDim.x + threadIdx.x;
    if (e >= E + N) return;
    int s = (e < E) ? src[e] : (e - E);
    int d = (e < E) ? dst[e] : (e - E);
#pragma unroll
    for (int h = 0; h < H; h++) {
        float t = lrelu(as_[s * H + h] + ad_[d * H + h]);
        float mv = funmap(m[d * H + h]);
        float v = __expf(t - mv);
        ex[(size_t)e * H + h] = v;
        atomicAdd(&ssum[d * H + h], v);
    }
}

// One block per edge; H*C threads = one channel each.
template <int H, int C>
__global__ void edge_agg(const int* __restrict__ src, const int* __restrict__ dst,
                         const float* __restrict__ Hf, const float* __restrict__ ex,
                         const float* __restrict__ ssum, float* __restrict__ out,
                         int E, int N) {
    const int e = blockIdx.x;
    const int t = threadIdx.x;  // [0, H*C)
    int s = (e < E) ? src[e] : (e - E);
    int d = (e < E) ? dst[e] : (e - E);
    const int h = t / C;
    float alpha = ex[(size_t)e * H + h] / (ssum[d * H + h] + 1e-16f);
    float v = Hf[(size_t)s * H * C + t] * alpha;
    atomicAdd(&out[(size_t)d * H * C + t], v);
}

extern "C" void kernel_launch(void* const* d_in, const int* in_sizes, int n_in,
                              void* d_out, int out_size, void* d_ws, size_t ws_size,
                              hipStream_t stream) {
    const float* x   = (const float*)d_in[0];
    const int*   ei  = (const int*)d_in[1];
    const float* W1  = (const float*)d_in[2];
    const float* a1s = (const float*)d_in[3];
    const float* a1d = (const float*)d_in[4];
    const float* b1  = (const float*)d_in[5];
    const float* W2  = (const float*)d_in[6];
    const float* a2s = (const float*)d_in[7];
    const float* a2d = (const float*)d_in[8];
    const float* b2  = (const float*)d_in[9];

    const int N = in_sizes[0] / 128;  // 50000
    const int E = in_sizes[1] / 2;    // 800000
    const int ET = E + N;             // with self-loops
    const int* srcIdx = ei;
    const int* dstIdx = ei + E;
    float* out = (float*)d_out;

    // ---- workspace carve-up ----
    char* w = (char*)d_ws;
    float*    h1   = (float*)w;  w += (size_t)N * 256 * 4;
    float*    out1 = (float*)w;  w += (size_t)N * 256 * 4;
    float*    h2   = (float*)w;  w += (size_t)N * 128 * 4;
    float*    as1  = (float*)w;  w += (size_t)N * 4 * 4;
    float*    ad1  = (float*)w;  w += (size_t)N * 4 * 4;
    unsigned* m1   = (unsigned*)w; w += (size_t)N * 4 * 4;
    float*    s1   = (float*)w;  w += (size_t)N * 4 * 4;
    float*    as2  = (float*)w;  w += (size_t)N * 4;
    float*    ad2  = (float*)w;  w += (size_t)N * 4;
    unsigned* m2   = (unsigned*)w; w += (size_t)N * 4;
    float*    s2   = (float*)w;  w += (size_t)N * 4;
    float*    ex1  = (float*)w;  w += (size_t)ET * 4 * 4;
    float*    ex2  = (float*)w;  w += (size_t)ET * 4;

    hipMemsetAsync(m1, 0, (size_t)N * 4 * 4, stream);
    hipMemsetAsync(s1, 0, (size_t)N * 4 * 4, stream);
    hipMemsetAsync(m2, 0, (size_t)N * 4, stream);
    hipMemsetAsync(s2, 0, (size_t)N * 4, stream);

    // bias-init the aggregation buffers (bias is added post-aggregation in GATConv)
    {
        long t1 = (long)N * 256;
        init_bias<<<(t1 + 255) / 256, 256, 0, stream>>>(out1, b1, t1, 256);
        long t2 = (long)N * 128;
        init_bias<<<(t2 + 255) / 256, 256, 0, stream>>>(out, b2, t2, 128);
    }

    // ---- layer 1 ----
    gemm_rows<128, 256, 32><<<(N + 31) / 32, 256, 0, stream>>>(x, W1, h1, N);
    attn_dots<4, 64><<<N, 256, 0, stream>>>(h1, a1s, a1d, as1, ad1);
    edge_max<4><<<(ET + 255) / 256, 256, 0, stream>>>(srcIdx, dstIdx, as1, ad1, m1, E, N);
    edge_expsum<4><<<(ET + 255) / 256, 256, 0, stream>>>(srcIdx, dstIdx, as1, ad1, m1, ex1, s1, E, N);
    edge_agg<4, 64><<<ET, 256, 0, stream>>>(srcIdx, dstIdx, h1, ex1, s1, out1, E, N);
    relu_inplace<<<((long)N * 256 + 255) / 256, 256, 0, stream>>>(out1, (long)N * 256);

    // ---- layer 2 ----
    gemm_rows<256, 128, 32><<<(N + 31) / 32, 128, 0, stream>>>(out1, W2, h2, N);
    attn_dots<1, 128><<<N, 128, 0, stream>>>(h2, a2s, a2d, as2, ad2);
    edge_max<1><<<(ET + 255) / 256, 256, 0, stream>>>(srcIdx, dstIdx, as2, ad2, m2, E, N);
    edge_expsum<1><<<(ET + 255) / 256, 256, 0, stream>>>(srcIdx, dstIdx, as2, ad2, m2, ex2, s2, E, N);
    edge_agg<1, 128><<<ET, 128, 0, stream>>>(srcIdx, dstIdx, h2, ex2, s2, out, E, N);
}

// Round 2
// 883.420 us; speedup vs baseline: 2.1692x; 2.1692x over previous
//
#include <hip/hip_runtime.h>
#include <math.h>

// N=50000, E=800000 (+N self loops), IN=128, HID=256, HEADS=4, C1=64, OUT=128
#define NEG_SLOPE 0.2f

__device__ __forceinline__ float lrelu(float t) {
    return t > 0.f ? t : NEG_SLOPE * t;
}

// ---------------- GEMM: Y[M,NC] = X[M,K] @ W[K,NC] ----------------
template <int K, int NC, int ROWS>
__global__ void gemm_rows(const float* __restrict__ X, const float* __restrict__ W,
                          float* __restrict__ Y, int M) {
    __shared__ float xs[ROWS * K];
    const int j = threadIdx.x;
    const int row0 = blockIdx.x * ROWS;

    const int TOT4 = ROWS * K / 4;
    for (int i = j; i < TOT4; i += NC) {
        int r = (i * 4) / K;
        float4 v = make_float4(0.f, 0.f, 0.f, 0.f);
        if (row0 + r < M) v = ((const float4*)X)[(size_t)row0 * (K / 4) + i];
        ((float4*)xs)[i] = v;
    }
    __syncthreads();

    float acc[ROWS];
#pragma unroll
    for (int r = 0; r < ROWS; r++) acc[r] = 0.f;

    for (int k = 0; k < K; k++) {
        float w = W[k * NC + j];
#pragma unroll
        for (int r = 0; r < ROWS; r++) acc[r] += xs[r * K + k] * w;
    }

#pragma unroll
    for (int r = 0; r < ROWS; r++) {
        if (row0 + r < M) Y[(size_t)(row0 + r) * NC + j] = acc[r];
    }
}

// ---------------- attention dot products ----------------
template <int H, int C>
__global__ void attn_dots(const float* __restrict__ Hf,
                          const float* __restrict__ a_src,
                          const float* __restrict__ a_dst,
                          float* __restrict__ as_out, float* __restrict__ ad_out) {
    const int n = blockIdx.x;
    const int t = threadIdx.x;  // [0, H*C)
    float hv = Hf[(size_t)n * H * C + t];
    float vs = hv * a_src[t];
    float vd = hv * a_dst[t];
#pragma unroll
    for (int off = 32; off > 0; off >>= 1) {
        vs += __shfl_down(vs, off, 64);
        vd += __shfl_down(vd, off, 64);
    }
    __shared__ float ps[H * C / 64], pd[H * C / 64];
    const int wave = t >> 6, lane = t & 63;
    if (lane == 0) { ps[wave] = vs; pd[wave] = vd; }
    __syncthreads();
    if (t < H) {
        float ss = 0.f, dd = 0.f;
#pragma unroll
        for (int w = 0; w < C / 64; w++) {
            ss += ps[t * (C / 64) + w];
            dd += pd[t * (C / 64) + w];
        }
        as_out[n * H + t] = ss;
        ad_out[n * H + t] = dd;
    }
}

// ---------------- CSR build (per-call; shared by both layers) ----------------
__global__ void hist_dst(const int* __restrict__ dst, int* __restrict__ cnt, int E) {
    int e = blockIdx.x * blockDim.x + threadIdx.x;
    if (e < E) atomicAdd(&cnt[dst[e]], 1);
}

// per-1024-chunk sums of (cnt[i]+1)
__global__ void chunk_sums(const int* __restrict__ cnt, int* __restrict__ chunkSum, int N) {
    __shared__ int sred[1024];
    int i = blockIdx.x * 1024 + threadIdx.x;
    int v = (i < N) ? cnt[i] + 1 : 0;
    sred[threadIdx.x] = v;
    __syncthreads();
    for (int off = 512; off > 0; off >>= 1) {
        if (threadIdx.x < off) sred[threadIdx.x] += sred[threadIdx.x + off];
        __syncthreads();
    }
    if (threadIdx.x == 0) chunkSum[blockIdx.x] = sred[0];
}

// single-wave exclusive scan of chunk sums (nChunk <= 64)
__global__ void scan_chunks(const int* __restrict__ chunkSum, int* __restrict__ chunkOff,
                            int nChunk, int* __restrict__ row_start, int N) {
    int t = threadIdx.x;
    int orig = (t < nChunk) ? chunkSum[t] : 0;
    int v = orig;
#pragma unroll
    for (int off = 1; off < 64; off <<= 1) {
        int up = __shfl_up(v, off, 64);
        if (t >= off) v += up;
    }
    if (t < nChunk) chunkOff[t] = v - orig;
    if (t == nChunk - 1) row_start[N] = v;
}

// per-chunk Hillis-Steele scan -> row_start, self-loop first, cursor
__global__ void build_rows(const int* __restrict__ cnt, const int* __restrict__ chunkOff,
                           int* __restrict__ row_start, int* __restrict__ eSrc,
                           int* __restrict__ cursor, int N) {
    __shared__ int buf[1024];
    int i = blockIdx.x * 1024 + threadIdx.x;
    int v = (i < N) ? cnt[i] + 1 : 0;
    buf[threadIdx.x] = v;
    __syncthreads();
    for (int off = 1; off < 1024; off <<= 1) {
        int add = (threadIdx.x >= off) ? buf[threadIdx.x - off] : 0;
        __syncthreads();
        buf[threadIdx.x] += add;
        __syncthreads();
    }
    if (i < N) {
        int excl = chunkOff[blockIdx.x] + buf[threadIdx.x] - v;
        row_start[i] = excl;
        eSrc[excl] = i;       // self-loop occupies slot 0 of each bucket
        cursor[i] = excl + 1;
    }
}

__global__ void scatter_edges(const int* __restrict__ src, const int* __restrict__ dst,
                              int* __restrict__ cursor, int* __restrict__ eSrc, int E) {
    int e = blockIdx.x * blockDim.x + threadIdx.x;
    if (e < E) {
        int pos = atomicAdd(&cursor[dst[e]], 1);
        eSrc[pos] = src[e];
    }
}

// ---------------- fused per-dst softmax + aggregation ----------------
// Block = H*C threads, one block per dst node. No atomics.
template <int H, int C, bool RELU>
__global__ void gat_aggregate(const int* __restrict__ row_start,
                              const int* __restrict__ eSrc,
                              const float* __restrict__ Hf,
                              const float* __restrict__ as_,
                              const float* __restrict__ ad_,
                              const float* __restrict__ bias,
                              float* __restrict__ out) {
    constexpr int B = H * C;
    constexpr int NSLOT = B / H;
    const int d = blockIdx.x;
    const int t = threadIdx.x;
    const int beg = row_start[d];
    const int deg = row_start[d + 1] - beg;

    __shared__ float red[B];
    __shared__ float mval[H], rinv[H];

    const int h = t & (H - 1);
    const int slot = t / H;
    const float adh = ad_[d * H + h];

    // phase 1: per-head max
    float lmax = -1e30f;
    for (int i = slot; i < deg; i += NSLOT) {
        int s = eSrc[beg + i];
        float v = lrelu(as_[s * H + h] + adh);
        lmax = fmaxf(lmax, v);
    }
    red[t] = lmax;
    __syncthreads();
    for (int off = B / 2; off >= H; off >>= 1) {
        if (t < off) red[t] = fmaxf(red[t], red[t + off]);
        __syncthreads();
    }
    if (t < H) mval[t] = red[t];
    __syncthreads();

    // phase 2: per-head sum of exp
    const float mh = mval[h];
    float lsum = 0.f;
    for (int i = slot; i < deg; i += NSLOT) {
        int s = eSrc[beg + i];
        float v = lrelu(as_[s * H + h] + adh);
        lsum += __expf(v - mh);
    }
    __syncthreads();  // red reuse
    red[t] = lsum;
    __syncthreads();
    for (int off = B / 2; off >= H; off >>= 1) {
        if (t < off) red[t] += red[t + off];
        __syncthreads();
    }
    if (t < H) rinv[t] = 1.f / (red[t] + 1e-16f);
    __syncthreads();

    // phase 3: weighted aggregation, thread = channel
    const int hc = t / C;
    const float m3 = mval[hc];
    const float ri = rinv[hc];
    const float ad3 = ad_[d * H + hc];
    float acc = 0.f;
    for (int i = 0; i < deg; i++) {
        int s = eSrc[beg + i];
        float v = lrelu(as_[s * H + hc] + ad3);
        float alpha = __expf(v - m3) * ri;
        acc += alpha * Hf[(size_t)s * B + t];
    }
    float r = acc + bias[t];
    if (RELU) r = fmaxf(r, 0.f);
    out[(size_t)d * B + t] = r;
}

extern "C" void kernel_launch(void* const* d_in, const int* in_sizes, int n_in,
                              void* d_out, int out_size, void* d_ws, size_t ws_size,
                              hipStream_t stream) {
    const float* x   = (const float*)d_in[0];
    const int*   ei  = (const int*)d_in[1];
    const float* W1  = (const float*)d_in[2];
    const float* a1s = (const float*)d_in[3];
    const float* a1d = (const float*)d_in[4];
    const float* b1  = (const float*)d_in[5];
    const float* W2  = (const float*)d_in[6];
    const float* a2s = (const float*)d_in[7];
    const float* a2d = (const float*)d_in[8];
    const float* b2  = (const float*)d_in[9];

    const int N = in_sizes[0] / 128;  // 50000
    const int E = in_sizes[1] / 2;    // 800000
    const int ET = E + N;
    const int* srcIdx = ei;
    const int* dstIdx = ei + E;
    float* out = (float*)d_out;

    // ---- workspace carve-up ----
    char* w = (char*)d_ws;
    float* h1   = (float*)w;  w += (size_t)N * 256 * 4;
    float* out1 = (float*)w;  w += (size_t)N * 256 * 4;
    float* h2   = (float*)w;  w += (size_t)N * 128 * 4;
    float* as1  = (float*)w;  w += (size_t)N * 4 * 4;
    float* ad1  = (float*)w;  w += (size_t)N * 4 * 4;
    float* as2  = (float*)w;  w += (size_t)N * 4;
    float* ad2  = (float*)w;  w += (size_t)N * 4;
    int* cnt       = (int*)w; w += (size_t)N * 4;
    int* row_start = (int*)w; w += (size_t)(N + 1) * 4;
    int* cursor    = (int*)w; w += (size_t)N * 4;
    int* chunkSum  = (int*)w; w += 64 * 4;
    int* chunkOff  = (int*)w; w += 64 * 4;
    int* eSrc      = (int*)w; w += (size_t)ET * 4;

    const int CH = 1024;
    const int nChunk = (N + CH - 1) / CH;  // 49

    // ---- CSR build (shared by both layers) ----
    hipMemsetAsync(cnt, 0, (size_t)N * 4, stream);
    hist_dst<<<(E + 255) / 256, 256, 0, stream>>>(dstIdx, cnt, E);
    chunk_sums<<<nChunk, 1024, 0, stream>>>(cnt, chunkSum, N);
    scan_chunks<<<1, 64, 0, stream>>>(chunkSum, chunkOff, nChunk, row_start, N);
    build_rows<<<nChunk, 1024, 0, stream>>>(cnt, chunkOff, row_start, eSrc, cursor, N);
    scatter_edges<<<(E + 255) / 256, 256, 0, stream>>>(srcIdx, dstIdx, cursor, eSrc, E);

    // ---- layer 1 ----
    gemm_rows<128, 256, 32><<<(N + 31) / 32, 256, 0, stream>>>(x, W1, h1, N);
    attn_dots<4, 64><<<N, 256, 0, stream>>>(h1, a1s, a1d, as1, ad1);
    gat_aggregate<4, 64, true><<<N, 256, 0, stream>>>(row_start, eSrc, h1, as1, ad1, b1, out1);

    // ---- layer 2 ----
    gemm_rows<256, 128, 32><<<(N + 31) / 32, 128, 0, stream>>>(out1, W2, h2, N);
    attn_dots<1, 128><<<N, 128, 0, stream>>>(h2, a2s, a2d, as2, ad2);
    gat_aggregate<1, 128, false><<<N, 128, 0, stream>>>(row_start, eSrc, h2, as2, ad2, b2, out);
}

// Round 3
// 742.920 us; speedup vs baseline: 2.5795x; 1.1891x over previous
//
#include <hip/hip_runtime.h>
#include <math.h>

// N=50000, E=800000 (+N self loops), IN=128, HID=256, HEADS=4, C1=64, OUT=128
#define NEG_SLOPE 0.2f

__device__ __forceinline__ float lrelu(float t) {
    return t > 0.f ? t : NEG_SLOPE * t;
}
__device__ __forceinline__ float bf2f(unsigned short u) {
    return __uint_as_float(((unsigned)u) << 16);
}
__device__ __forceinline__ unsigned short f2bf(float f) {
    unsigned u = __float_as_uint(f);
    unsigned r = (u + 0x7fff + ((u >> 16) & 1)) >> 16;  // round-to-nearest-even
    return (unsigned short)r;
}

// ---------------- GEMM: Y[M,NC] = X[M,K] @ W[K,NC], dual fp32+bf16 output ----
template <int K, int NC, int ROWS>
__global__ void gemm_rows(const float* __restrict__ X, const float* __restrict__ W,
                          float* __restrict__ Y, unsigned short* __restrict__ Yb, int M) {
    __shared__ float xs[ROWS * K];
    const int j = threadIdx.x;
    const int row0 = blockIdx.x * ROWS;

    const int TOT4 = ROWS * K / 4;
    for (int i = j; i < TOT4; i += NC) {
        int r = (i * 4) / K;
        float4 v = make_float4(0.f, 0.f, 0.f, 0.f);
        if (row0 + r < M) v = ((const float4*)X)[(size_t)row0 * (K / 4) + i];
        ((float4*)xs)[i] = v;
    }
    __syncthreads();

    float acc[ROWS];
#pragma unroll
    for (int r = 0; r < ROWS; r++) acc[r] = 0.f;

    for (int k = 0; k < K; k++) {
        float w = W[k * NC + j];
#pragma unroll
        for (int r = 0; r < ROWS; r++) acc[r] += xs[r * K + k] * w;
    }

#pragma unroll
    for (int r = 0; r < ROWS; r++) {
        if (row0 + r < M) {
            Y[(size_t)(row0 + r) * NC + j] = acc[r];
            Yb[(size_t)(row0 + r) * NC + j] = f2bf(acc[r]);
        }
    }
}

// ---------------- attention dot products (fp32 h) ----------------
template <int H, int C>
__global__ void attn_dots(const float* __restrict__ Hf,
                          const float* __restrict__ a_src,
                          const float* __restrict__ a_dst,
                          float* __restrict__ as_out, float* __restrict__ ad_out) {
    const int n = blockIdx.x;
    const int t = threadIdx.x;  // [0, H*C)
    float hv = Hf[(size_t)n * H * C + t];
    float vs = hv * a_src[t];
    float vd = hv * a_dst[t];
#pragma unroll
    for (int off = 32; off > 0; off >>= 1) {
        vs += __shfl_down(vs, off, 64);
        vd += __shfl_down(vd, off, 64);
    }
    __shared__ float ps[H * C / 64], pd[H * C / 64];
    const int wave = t >> 6, lane = t & 63;
    if (lane == 0) { ps[wave] = vs; pd[wave] = vd; }
    __syncthreads();
    if (t < H) {
        float ss = 0.f, dd = 0.f;
#pragma unroll
        for (int w = 0; w < C / 64; w++) {
            ss += ps[t * (C / 64) + w];
            dd += pd[t * (C / 64) + w];
        }
        as_out[n * H + t] = ss;
        ad_out[n * H + t] = dd;
    }
}

// ---------------- CSR build (per-call; shared by both layers) ----------------
__global__ void hist_dst(const int* __restrict__ dst, int* __restrict__ cnt, int E) {
    int e = blockIdx.x * blockDim.x + threadIdx.x;
    if (e < E) atomicAdd(&cnt[dst[e]], 1);
}

__global__ void chunk_sums(const int* __restrict__ cnt, int* __restrict__ chunkSum, int N) {
    __shared__ int sred[1024];
    int i = blockIdx.x * 1024 + threadIdx.x;
    int v = (i < N) ? cnt[i] + 1 : 0;
    sred[threadIdx.x] = v;
    __syncthreads();
    for (int off = 512; off > 0; off >>= 1) {
        if (threadIdx.x < off) sred[threadIdx.x] += sred[threadIdx.x + off];
        __syncthreads();
    }
    if (threadIdx.x == 0) chunkSum[blockIdx.x] = sred[0];
}

__global__ void scan_chunks(const int* __restrict__ chunkSum, int* __restrict__ chunkOff,
                            int nChunk, int* __restrict__ row_start, int N) {
    int t = threadIdx.x;
    int orig = (t < nChunk) ? chunkSum[t] : 0;
    int v = orig;
#pragma unroll
    for (int off = 1; off < 64; off <<= 1) {
        int up = __shfl_up(v, off, 64);
        if (t >= off) v += up;
    }
    if (t < nChunk) chunkOff[t] = v - orig;
    if (t == nChunk - 1) row_start[N] = v;
}

__global__ void build_rows(const int* __restrict__ cnt, const int* __restrict__ chunkOff,
                           int* __restrict__ row_start, int* __restrict__ eSrc,
                           int* __restrict__ cursor, int N) {
    __shared__ int buf[1024];
    int i = blockIdx.x * 1024 + threadIdx.x;
    int v = (i < N) ? cnt[i] + 1 : 0;
    buf[threadIdx.x] = v;
    __syncthreads();
    for (int off = 1; off < 1024; off <<= 1) {
        int add = (threadIdx.x >= off) ? buf[threadIdx.x - off] : 0;
        __syncthreads();
        buf[threadIdx.x] += add;
        __syncthreads();
    }
    if (i < N) {
        int excl = chunkOff[blockIdx.x] + buf[threadIdx.x] - v;
        row_start[i] = excl;
        eSrc[excl] = i;       // self-loop occupies slot 0 of each bucket
        cursor[i] = excl + 1;
    }
}

__global__ void scatter_edges(const int* __restrict__ src, const int* __restrict__ dst,
                              int* __restrict__ cursor, int* __restrict__ eSrc, int E) {
    int e = blockIdx.x * blockDim.x + threadIdx.x;
    if (e < E) {
        int pos = atomicAdd(&cursor[dst[e]], 1);
        eSrc[pos] = src[e];
    }
}

// ---------------- fused per-dst softmax + aggregation ----------------
// Block = H*C threads, one block per dst node. bf16 feature gather, LDS alphas.
template <int H, int C, bool RELU>
__global__ void gat_aggregate(const int* __restrict__ row_start,
                              const int* __restrict__ eSrc,
                              const unsigned short* __restrict__ Hb,
                              const float* __restrict__ as_,
                              const float* __restrict__ ad_,
                              const float* __restrict__ bias,
                              float* __restrict__ out) {
    constexpr int B = H * C;
    constexpr int NSLOT = B / H;   // threads per head in phases 1-2
    constexpr int TILE = B / H;    // edges per alpha tile in phase 3
    const int d = blockIdx.x;
    const int t = threadIdx.x;
    const int beg = row_start[d];
    const int deg = row_start[d + 1] - beg;

    __shared__ float red[B];
    __shared__ float mval[H], rinv[H];
    __shared__ float alphaS[TILE * H];
    __shared__ int sSm[TILE];

    const int h = t & (H - 1);
    const int slot = t / H;
    const float adh = ad_[d * H + h];

    // phase 1: per-head max
    float lmax = -1e30f;
    for (int i = slot; i < deg; i += NSLOT) {
        int s = eSrc[beg + i];
        float v = lrelu(as_[s * H + h] + adh);
        lmax = fmaxf(lmax, v);
    }
    red[t] = lmax;
    __syncthreads();
    for (int off = B / 2; off >= H; off >>= 1) {
        if (t < off) red[t] = fmaxf(red[t], red[t + off]);
        __syncthreads();
    }
    if (t < H) mval[t] = red[t];
    __syncthreads();

    // phase 2: per-head sum of exp
    const float mh = mval[h];
    float lsum = 0.f;
    for (int i = slot; i < deg; i += NSLOT) {
        int s = eSrc[beg + i];
        float v = lrelu(as_[s * H + h] + adh);
        lsum += __expf(v - mh);
    }
    __syncthreads();
    red[t] = lsum;
    __syncthreads();
    for (int off = B / 2; off >= H; off >>= 1) {
        if (t < off) red[t] += red[t + off];
        __syncthreads();
    }
    if (t < H) rinv[t] = 1.f / (red[t] + 1e-16f);
    __syncthreads();

    // phase 3: tile alphas into LDS, then bf16 gather + fma per channel
    const int hc = t / C;
    float acc = 0.f;
    for (int base = 0; base < deg; base += TILE) {
        int n = deg - base; if (n > TILE) n = TILE;
        __syncthreads();  // alphaS reuse hazard
        if (t < n * H) {
            int i = t / H, hh = t % H;
            int s = eSrc[beg + base + i];
            if (hh == 0) sSm[i] = s;
            float v = lrelu(as_[s * H + hh] + ad_[d * H + hh]);
            alphaS[i * H + hh] = __expf(v - mval[hh]) * rinv[hh];
        }
        __syncthreads();
        for (int i = 0; i < n; i++) {
            int s = sSm[i];
            acc += alphaS[i * H + hc] * bf2f(Hb[(size_t)s * B + t]);
        }
    }
    float r = acc + bias[t];
    if (RELU) r = fmaxf(r, 0.f);
    out[(size_t)d * B + t] = r;
}

extern "C" void kernel_launch(void* const* d_in, const int* in_sizes, int n_in,
                              void* d_out, int out_size, void* d_ws, size_t ws_size,
                              hipStream_t stream) {
    const float* x   = (const float*)d_in[0];
    const int*   ei  = (const int*)d_in[1];
    const float* W1  = (const float*)d_in[2];
    const float* a1s = (const float*)d_in[3];
    const float* a1d = (const float*)d_in[4];
    const float* b1  = (const float*)d_in[5];
    const float* W2  = (const float*)d_in[6];
    const float* a2s = (const float*)d_in[7];
    const float* a2d = (const float*)d_in[8];
    const float* b2  = (const float*)d_in[9];

    const int N = in_sizes[0] / 128;  // 50000
    const int E = in_sizes[1] / 2;    // 800000
    const int ET = E + N;
    const int* srcIdx = ei;
    const int* dstIdx = ei + E;
    float* out = (float*)d_out;

    // ---- workspace carve-up ----
    char* w = (char*)d_ws;
    float* h1   = (float*)w;  w += (size_t)N * 256 * 4;
    float* out1 = (float*)w;  w += (size_t)N * 256 * 4;
    float* h2   = (float*)w;  w += (size_t)N * 128 * 4;
    unsigned short* h1b = (unsigned short*)w; w += (size_t)N * 256 * 2;
    unsigned short* h2b = (unsigned short*)w; w += (size_t)N * 128 * 2;
    float* as1  = (float*)w;  w += (size_t)N * 4 * 4;
    float* ad1  = (float*)w;  w += (size_t)N * 4 * 4;
    float* as2  = (float*)w;  w += (size_t)N * 4;
    float* ad2  = (float*)w;  w += (size_t)N * 4;
    int* cnt       = (int*)w; w += (size_t)N * 4;
    int* row_start = (int*)w; w += (size_t)(N + 1) * 4;
    int* cursor    = (int*)w; w += (size_t)N * 4;
    int* chunkSum  = (int*)w; w += 64 * 4;
    int* chunkOff  = (int*)w; w += 64 * 4;
    int* eSrc      = (int*)w; w += (size_t)ET * 4;

    const int CH = 1024;
    const int nChunk = (N + CH - 1) / CH;  // 49

    // ---- CSR build (shared by both layers) ----
    hipMemsetAsync(cnt, 0, (size_t)N * 4, stream);
    hist_dst<<<(E + 255) / 256, 256, 0, stream>>>(dstIdx, cnt, E);
    chunk_sums<<<nChunk, 1024, 0, stream>>>(cnt, chunkSum, N);
    scan_chunks<<<1, 64, 0, stream>>>(chunkSum, chunkOff, nChunk, row_start, N);
    build_rows<<<nChunk, 1024, 0, stream>>>(cnt, chunkOff, row_start, eSrc, cursor, N);
    scatter_edges<<<(E + 255) / 256, 256, 0, stream>>>(srcIdx, dstIdx, cursor, eSrc, E);

    // ---- layer 1 ----
    gemm_rows<128, 256, 32><<<(N + 31) / 32, 256, 0, stream>>>(x, W1, h1, h1b, N);
    attn_dots<4, 64><<<N, 256, 0, stream>>>(h1, a1s, a1d, as1, ad1);
    gat_aggregate<4, 64, true><<<N, 256, 0, stream>>>(row_start, eSrc, h1b, as1, ad1, b1, out1);

    // ---- layer 2 ----
    gemm_rows<256, 128, 32><<<(N + 31) / 32, 128, 0, stream>>>(out1, W2, h2, h2b, N);
    attn_dots<1, 128><<<N, 128, 0, stream>>>(h2, a2s, a2d, as2, ad2);
    gat_aggregate<1, 128, false><<<N, 128, 0, stream>>>(row_start, eSrc, h2b, as2, ad2, b2, out);
}

// Round 4
// 499.503 us; speedup vs baseline: 3.8365x; 1.4873x over previous
//
#include <hip/hip_runtime.h>
#include <math.h>

// N=50000, E=800000 (+N self loops), IN=128, HID=256, HEADS=4, C1=64, OUT=128
#define NEG_SLOPE 0.2f

typedef __attribute__((ext_vector_type(8))) short bf16x8;
typedef __attribute__((ext_vector_type(4))) float f32x4;

__device__ __forceinline__ float lrelu(float t) {
    return t > 0.f ? t : NEG_SLOPE * t;
}
__device__ __forceinline__ float bf2f(unsigned short u) {
    return __uint_as_float(((unsigned)u) << 16);
}
__device__ __forceinline__ unsigned short f2bf(float f) {
    unsigned u = __float_as_uint(f);
    unsigned r = (u + 0x7fff + ((u >> 16) & 1)) >> 16;  // RNE
    return (unsigned short)r;
}

// ---------------- small prep kernels ----------------
__global__ void cast_pad_bf16(const float* __restrict__ X, unsigned short* __restrict__ Xb,
                              long valid, long total) {
    long i = (long)blockIdx.x * blockDim.x + threadIdx.x;
    if (i < total) Xb[i] = (i < valid) ? f2bf(X[i]) : (unsigned short)0;
}

__global__ void zero_u16(unsigned short* __restrict__ p, long n) {
    long i = (long)blockIdx.x * blockDim.x + threadIdx.x;
    if (i < n) p[i] = 0;
}

// Wt[n*K+k] = bf16(W[k*N+n])
template <int K, int N>
__global__ void transpose_cast(const float* __restrict__ W, unsigned short* __restrict__ Wt) {
    int i = blockIdx.x * blockDim.x + threadIdx.x;
    if (i < K * N) {
        int n = i / K, k = i % K;
        Wt[i] = f2bf(W[k * N + n]);
    }
}

// vsd[j*K+k]: j<H -> sum_c W[k][h*C+c]*a_src[h][c]; j>=H -> a_dst
template <int K, int H, int C>
__global__ void proj_a(const float* __restrict__ W, const float* __restrict__ a_s,
                       const float* __restrict__ a_d, float* __restrict__ vsd) {
    int i = blockIdx.x * blockDim.x + threadIdx.x;  // [0, K*H)
    if (i >= K * H) return;
    int k = i / H, h = i % H;
    float s = 0.f, d = 0.f;
    for (int c = 0; c < C; c++) {
        float w = W[k * (H * C) + h * C + c];
        s += w * a_s[h * C + c];
        d += w * a_d[h * C + c];
    }
    vsd[h * K + k] = s;
    vsd[(H + h) * K + k] = d;
}

// as/ad[n,h] = X[n,:] @ vsd[j,:]  (fp32, exact logits). One wave per node.
template <int K, int H>
__global__ void gemv_attn(const float* __restrict__ X, const float* __restrict__ vsd,
                          float* __restrict__ as_, float* __restrict__ ad_, int M) {
    __shared__ float vs[2 * H * K];
    int t = threadIdx.x;
    for (int i = t; i < 2 * H * K; i += 256) vs[i] = vsd[i];
    __syncthreads();
    int wave = t >> 6, lane = t & 63;
    int n = blockIdx.x * 4 + wave;
    if (n >= M) return;
    float acc[2 * H];
#pragma unroll
    for (int j = 0; j < 2 * H; j++) acc[j] = 0.f;
#pragma unroll
    for (int i = 0; i < K / 64; i++) {
        float xv = X[(size_t)n * K + i * 64 + lane];
#pragma unroll
        for (int j = 0; j < 2 * H; j++) acc[j] += xv * vs[j * K + i * 64 + lane];
    }
#pragma unroll
    for (int off = 32; off > 0; off >>= 1) {
#pragma unroll
        for (int j = 0; j < 2 * H; j++) acc[j] += __shfl_down(acc[j], off, 64);
    }
    if (lane == 0) {
#pragma unroll
        for (int h = 0; h < H; h++) {
            as_[n * H + h] = acc[h];
            ad_[n * H + h] = acc[H + h];
        }
    }
}

// ---------------- MFMA GEMM: Cb[M,N](bf16) = A[M_pad,K](bf16) @ Bt[N,K]^T ----
// tile 128x64, block 256 thr (4 waves), wave does 32 rows x 64 cols.
template <int K, int N>
__global__ __launch_bounds__(256) void gemm_mfma(const unsigned short* __restrict__ A,
                                                 const unsigned short* __restrict__ Bt,
                                                 unsigned short* __restrict__ Cb, int M) {
    constexpr int LDT = 72;  // pad: +8 bf16 -> 2-way-free LDS pattern
    __shared__ __align__(16) short As[128 * LDT];
    __shared__ __align__(16) short Bs[64 * LDT];
    const int t = threadIdx.x;
    const int wave = t >> 6, lane = t & 63;
    const int row0 = blockIdx.x * 128;
    const int n0 = blockIdx.y * 64;

    f32x4 acc[2][4];
#pragma unroll
    for (int mt = 0; mt < 2; mt++)
#pragma unroll
        for (int nt = 0; nt < 4; nt++) acc[mt][nt] = (f32x4){0.f, 0.f, 0.f, 0.f};

    const int r = t >> 3, c8 = (t & 7) * 8;
    for (int kc = 0; kc < K; kc += 64) {
        const unsigned short* srcA = A + (size_t)row0 * K + kc;
#pragma unroll
        for (int p = 0; p < 4; p++) {
            int rr = r + p * 32;
            *(bf16x8*)&As[rr * LDT + c8] = *(const bf16x8*)&srcA[(size_t)rr * K + c8];
        }
        const unsigned short* srcB = Bt + (size_t)n0 * K + kc;
#pragma unroll
        for (int p = 0; p < 2; p++) {
            int rr = r + p * 32;
            *(bf16x8*)&Bs[rr * LDT + c8] = *(const bf16x8*)&srcB[(size_t)rr * K + c8];
        }
        __syncthreads();

        const int mbase = wave * 32 + (lane & 15);
        const int quad = lane >> 4;
#pragma unroll
        for (int ks = 0; ks < 2; ks++) {
            int ko = ks * 32 + quad * 8;
            bf16x8 a0 = *(const bf16x8*)&As[mbase * LDT + ko];
            bf16x8 a1 = *(const bf16x8*)&As[(mbase + 16) * LDT + ko];
#pragma unroll
            for (int nt = 0; nt < 4; nt++) {
                bf16x8 b = *(const bf16x8*)&Bs[((lane & 15) + nt * 16) * LDT + ko];
                acc[0][nt] = __builtin_amdgcn_mfma_f32_16x16x32_bf16(a0, b, acc[0][nt], 0, 0, 0);
                acc[1][nt] = __builtin_amdgcn_mfma_f32_16x16x32_bf16(a1, b, acc[1][nt], 0, 0, 0);
            }
        }
        __syncthreads();
    }

    // epilogue: C/D layout col=lane&15, row=(lane>>4)*4+reg
    const int colb = n0 + (lane & 15);
    const int rquad = (lane >> 4) * 4;
#pragma unroll
    for (int mt = 0; mt < 2; mt++) {
        int rb = row0 + wave * 32 + mt * 16 + rquad;
#pragma unroll
        for (int nt = 0; nt < 4; nt++) {
#pragma unroll
            for (int rr2 = 0; rr2 < 4; rr2++) {
                int row = rb + rr2;
                if (row < M) Cb[(size_t)row * N + colb + nt * 16] = f2bf(acc[mt][nt][rr2]);
            }
        }
    }
}

// ---------------- CSR build ----------------
__global__ void hist_dst(const int* __restrict__ dst, int* __restrict__ cnt, int E) {
    int e = blockIdx.x * blockDim.x + threadIdx.x;
    if (e < E) atomicAdd(&cnt[dst[e]], 1);
}

__global__ void chunk_sums(const int* __restrict__ cnt, int* __restrict__ chunkSum, int N) {
    __shared__ int sred[1024];
    int i = blockIdx.x * 1024 + threadIdx.x;
    int v = (i < N) ? cnt[i] + 1 : 0;
    sred[threadIdx.x] = v;
    __syncthreads();
    for (int off = 512; off > 0; off >>= 1) {
        if (threadIdx.x < off) sred[threadIdx.x] += sred[threadIdx.x + off];
        __syncthreads();
    }
    if (threadIdx.x == 0) chunkSum[blockIdx.x] = sred[0];
}

__global__ void scan_chunks(const int* __restrict__ chunkSum, int* __restrict__ chunkOff,
                            int nChunk, int* __restrict__ row_start, int N) {
    int t = threadIdx.x;
    int orig = (t < nChunk) ? chunkSum[t] : 0;
    int v = orig;
#pragma unroll
    for (int off = 1; off < 64; off <<= 1) {
        int up = __shfl_up(v, off, 64);
        if (t >= off) v += up;
    }
    if (t < nChunk) chunkOff[t] = v - orig;
    if (t == nChunk - 1) row_start[N] = v;
}

__global__ void build_rows(const int* __restrict__ cnt, const int* __restrict__ chunkOff,
                           int* __restrict__ row_start, int* __restrict__ eSrc,
                           int* __restrict__ cursor, int N) {
    __shared__ int buf[1024];
    int i = blockIdx.x * 1024 + threadIdx.x;
    int v = (i < N) ? cnt[i] + 1 : 0;
    buf[threadIdx.x] = v;
    __syncthreads();
    for (int off = 1; off < 1024; off <<= 1) {
        int add = (threadIdx.x >= off) ? buf[threadIdx.x - off] : 0;
        __syncthreads();
        buf[threadIdx.x] += add;
        __syncthreads();
    }
    if (i < N) {
        int excl = chunkOff[blockIdx.x] + buf[threadIdx.x] - v;
        row_start[i] = excl;
        eSrc[excl] = i;  // self-loop first
        cursor[i] = excl + 1;
    }
}

__global__ void scatter_edges(const int* __restrict__ src, const int* __restrict__ dst,
                              int* __restrict__ cursor, int* __restrict__ eSrc, int E) {
    int e = blockIdx.x * blockDim.x + threadIdx.x;
    if (e < E) {
        int pos = atomicAdd(&cursor[dst[e]], 1);
        eSrc[pos] = src[e];
    }
}

// ---------------- fused per-dst softmax + aggregation ----------------
template <int H, int C, bool RELU, bool WRITEB>
__global__ void gat_aggregate(const int* __restrict__ row_start,
                              const int* __restrict__ eSrc,
                              const unsigned short* __restrict__ Hb,
                              const float* __restrict__ as_,
                              const float* __restrict__ ad_,
                              const float* __restrict__ bias,
                              float* __restrict__ out,
                              unsigned short* __restrict__ outb) {
    constexpr int B = H * C;
    constexpr int NSLOT = B / H;
    constexpr int TILE = B / H;
    const int d = blockIdx.x;
    const int t = threadIdx.x;
    const int beg = row_start[d];
    const int deg = row_start[d + 1] - beg;

    __shared__ float red[B];
    __shared__ float mval[H], rinv[H];
    __shared__ float alphaS[TILE * H];
    __shared__ int sSm[TILE];

    const int h = t & (H - 1);
    const int slot = t / H;
    const float adh = ad_[d * H + h];

    float lmax = -1e30f;
    for (int i = slot; i < deg; i += NSLOT) {
        int s = eSrc[beg + i];
        float v = lrelu(as_[s * H + h] + adh);
        lmax = fmaxf(lmax, v);
    }
    red[t] = lmax;
    __syncthreads();
    for (int off = B / 2; off >= H; off >>= 1) {
        if (t < off) red[t] = fmaxf(red[t], red[t + off]);
        __syncthreads();
    }
    if (t < H) mval[t] = red[t];
    __syncthreads();

    const float mh = mval[h];
    float lsum = 0.f;
    for (int i = slot; i < deg; i += NSLOT) {
        int s = eSrc[beg + i];
        float v = lrelu(as_[s * H + h] + adh);
        lsum += __expf(v - mh);
    }
    __syncthreads();
    red[t] = lsum;
    __syncthreads();
    for (int off = B / 2; off >= H; off >>= 1) {
        if (t < off) red[t] += red[t + off];
        __syncthreads();
    }
    if (t < H) rinv[t] = 1.f / (red[t] + 1e-16f);
    __syncthreads();

    const int hc = t / C;
    float acc = 0.f;
    for (int base = 0; base < deg; base += TILE) {
        int n = deg - base; if (n > TILE) n = TILE;
        __syncthreads();
        if (t < n * H) {
            int i = t / H, hh = t % H;
            int s = eSrc[beg + base + i];
            if (hh == 0) sSm[i] = s;
            float v = lrelu(as_[s * H + hh] + ad_[d * H + hh]);
            alphaS[i * H + hh] = __expf(v - mval[hh]) * rinv[hh];
        }
        __syncthreads();
        for (int i = 0; i < n; i++) {
            int s = sSm[i];
            acc += alphaS[i * H + hc] * bf2f(Hb[(size_t)s * B + t]);
        }
    }
    float rres = acc + bias[t];
    if (RELU) rres = fmaxf(rres, 0.f);
    out[(size_t)d * B + t] = rres;
    if (WRITEB) outb[(size_t)d * B + t] = f2bf(rres);
}

extern "C" void kernel_launch(void* const* d_in, const int* in_sizes, int n_in,
                              void* d_out, int out_size, void* d_ws, size_t ws_size,
                              hipStream_t stream) {
    const float* x   = (const float*)d_in[0];
    const int*   ei  = (const int*)d_in[1];
    const float* W1  = (const float*)d_in[2];
    const float* a1s = (const float*)d_in[3];
    const float* a1d = (const float*)d_in[4];
    const float* b1  = (const float*)d_in[5];
    const float* W2  = (const float*)d_in[6];
    const float* a2s = (const float*)d_in[7];
    const float* a2d = (const float*)d_in[8];
    const float* b2  = (const float*)d_in[9];

    const int N = in_sizes[0] / 128;  // 50000
    const int E = in_sizes[1] / 2;    // 800000
    const int ET = E + N;
    const int* srcIdx = ei;
    const int* dstIdx = ei + E;
    float* out = (float*)d_out;

    const int MT = (N + 127) / 128;        // 391
    const int M_pad = MT * 128;            // 50048

    // ---- workspace carve-up ----
    char* w = (char*)d_ws;
    unsigned short* x_bf  = (unsigned short*)w; w += (size_t)M_pad * 128 * 2;
    unsigned short* h1b   = (unsigned short*)w; w += (size_t)N * 256 * 2;
    float*          out1  = (float*)w;          w += (size_t)N * 256 * 4;
    unsigned short* out1b = (unsigned short*)w; w += (size_t)M_pad * 256 * 2;
    unsigned short* h2b   = (unsigned short*)w; w += (size_t)N * 128 * 2;
    unsigned short* W1t   = (unsigned short*)w; w += (size_t)128 * 256 * 2;
    unsigned short* W2t   = (unsigned short*)w; w += (size_t)256 * 128 * 2;
    float* vsd1 = (float*)w; w += (size_t)128 * 8 * 4;
    float* vsd2 = (float*)w; w += (size_t)256 * 2 * 4;
    float* as1  = (float*)w; w += (size_t)N * 4 * 4;
    float* ad1  = (float*)w; w += (size_t)N * 4 * 4;
    float* as2  = (float*)w; w += (size_t)N * 4;
    float* ad2  = (float*)w; w += (size_t)N * 4;
    int* cnt       = (int*)w; w += (size_t)N * 4;
    int* row_start = (int*)w; w += (size_t)(N + 1) * 4;
    int* cursor    = (int*)w; w += (size_t)N * 4;
    int* chunkSum  = (int*)w; w += 64 * 4;
    int* chunkOff  = (int*)w; w += 64 * 4;
    int* eSrc      = (int*)w; w += (size_t)ET * 4;

    const int CH = 1024;
    const int nChunk = (N + CH - 1) / CH;  // 49

    // ---- CSR build ----
    hipMemsetAsync(cnt, 0, (size_t)N * 4, stream);
    hist_dst<<<(E + 255) / 256, 256, 0, stream>>>(dstIdx, cnt, E);
    chunk_sums<<<nChunk, 1024, 0, stream>>>(cnt, chunkSum, N);
    scan_chunks<<<1, 64, 0, stream>>>(chunkSum, chunkOff, nChunk, row_start, N);
    build_rows<<<nChunk, 1024, 0, stream>>>(cnt, chunkOff, row_start, eSrc, cursor, N);
    scatter_edges<<<(E + 255) / 256, 256, 0, stream>>>(srcIdx, dstIdx, cursor, eSrc, E);

    // ---- prep: casts + projections ----
    {
        long tot = (long)M_pad * 128;
        cast_pad_bf16<<<(tot + 255) / 256, 256, 0, stream>>>(x, x_bf, (long)N * 128, tot);
        transpose_cast<128, 256><<<(128 * 256 + 255) / 256, 256, 0, stream>>>(W1, W1t);
        transpose_cast<256, 128><<<(256 * 128 + 255) / 256, 256, 0, stream>>>(W2, W2t);
        proj_a<128, 4, 64><<<2, 256, 0, stream>>>(W1, a1s, a1d, vsd1);
        proj_a<256, 1, 128><<<1, 256, 0, stream>>>(W2, a2s, a2d, vsd2);
        long padn = (long)(M_pad - N) * 256;
        zero_u16<<<(padn + 255) / 256, 256, 0, stream>>>(out1b + (size_t)N * 256, padn);
    }

    // ---- layer 1 ----
    gemm_mfma<128, 256><<<dim3(MT, 4), 256, 0, stream>>>(x_bf, W1t, h1b, N);
    gemv_attn<128, 4><<<(N + 3) / 4, 256, 0, stream>>>(x, vsd1, as1, ad1, N);
    gat_aggregate<4, 64, true, true><<<N, 256, 0, stream>>>(row_start, eSrc, h1b, as1, ad1, b1, out1, out1b);

    // ---- layer 2 ----
    gemm_mfma<256, 128><<<dim3(MT, 2), 256, 0, stream>>>(out1b, W2t, h2b, N);
    gemv_attn<256, 1><<<(N + 3) / 4, 256, 0, stream>>>(out1, vsd2, as2, ad2, N);
    gat_aggregate<1, 128, false, false><<<N, 128, 0, stream>>>(row_start, eSrc, h2b, as2, ad2, b2, out, nullptr);
}